// Round 14
// baseline (115.183 us; speedup 1.0000x reference)
//
#include <hip/hip_runtime.h>
#include <hip/hip_bf16.h>

typedef __attribute__((ext_vector_type(8))) short bf16x8;
typedef __attribute__((ext_vector_type(4))) float floatx4;

#define NB 128
#define NT 256
#define NC 384
#define NH 8
#define ND 48
#define CPLANE (128 * 8 * 256 * 48)  // elems per qkv component plane

static __device__ __forceinline__ unsigned short f2bf(float f) {
  __hip_bfloat16 h = __float2bfloat16(f);
  return __builtin_bit_cast(unsigned short, h);
}

static __device__ __forceinline__ void gload16(const unsigned short* g, unsigned short* l) {
  __builtin_amdgcn_global_load_lds(
      (const __attribute__((address_space(1))) void*)g,
      (__attribute__((address_space(3))) void*)l, 16, 0, 0);
}

static __device__ __forceinline__ void gload16f(const float* g, float* l) {
  __builtin_amdgcn_global_load_lds(
      (const __attribute__((address_space(1))) void*)g,
      (__attribute__((address_space(3))) void*)l, 16, 0, 0);
}

// ---------------- Prep: W-only now. W_qkv^T -> [1152][384] bf16,
//                  W_proj^T (gate folded) -> [384][384] bf16.
__global__ __launch_bounds__(256) void k_prep(const float* __restrict__ Wq,
                                              const float* __restrict__ Wp,
                                              const float* __restrict__ gate,
                                              unsigned short* __restrict__ WqT,
                                              unsigned short* __restrict__ WpT) {
  const int blk = blockIdx.x;
  const int t = threadIdx.x;
  __shared__ float T[64][65];
  const float* src;
  unsigned short* dst;
  int N, kt, nt;
  const bool isWp = (blk >= 108);
  if (!isWp) { src = Wq; dst = WqT; N = 1152; kt = blk / 18; nt = blk % 18; }
  else { int b2 = blk - 108; src = Wp; dst = WpT; N = 384; kt = b2 / 6; nt = b2 % 6; }
  const int k0 = kt * 64, n0 = nt * 64;
  const int r = t >> 2, c = (t & 3) * 16;
  const float* s = src + (size_t)(k0 + r) * N + n0 + c;
#pragma unroll
  for (int i = 0; i < 4; ++i) *(float4*)&T[r][c + i * 4] = ((const float4*)s)[i];
  __syncthreads();
  float gv[16];
  if (isWp) {
#pragma unroll
    for (int i = 0; i < 4; ++i) *(float4*)&gv[i * 4] = ((const float4*)(gate + k0 + c))[i];
  } else {
#pragma unroll
    for (int i = 0; i < 16; ++i) gv[i] = 1.f;
  }
  unsigned short o[16];
#pragma unroll
  for (int i = 0; i < 16; ++i) o[i] = f2bf(T[c + i][r] * gv[i]);
  unsigned short* dp = dst + (size_t)(n0 + r) * 384 + k0 + c;
  *(bf16x8*)dp = *(bf16x8*)&o[0];
  *(bf16x8*)(dp + 8) = *(bf16x8*)&o[8];
}

// ====== k_qkv: A staged as RAW FP32 (no prep pass), B bf16; r12 sync skeleton ======
// A: 128 rows x 32 k fp32, 16B chunks kc 0..7 per row, source-swizzled kc^(row&7).
// B: r12-proven bf16 staging.  6 loads/thread/iter -> vmcnt(6) steady.
#define STAGE_QF(k0, buf)                                                            \
  {                                                                                  \
    _Pragma("unroll") for (int l_ = 0; l_ < 4; ++l_) {                               \
      const int cid_ = l_ * 256 + t;                                                 \
      const int row_ = cid_ >> 3, kc_ = cid_ & 7;                                    \
      const int kcs_ = kc_ ^ (row_ & 7);                                             \
      gload16f(xg + (size_t)(m0 + row_) * 384 + (k0) + kcs_ * 4,                     \
               Asf + (buf) * 4096 + (l_ * 256 + w * 64) * 4);                        \
    }                                                                                \
    {                                                                                \
      const int r0_ = w * 32 + (lane >> 2), sw0_ = 8 * ((lane & 3) ^ ((r0_ >> 1) & 3)); \
      const int r1_ = r0_ + 16, sw1_ = 8 * ((lane & 3) ^ ((r1_ >> 1) & 3));          \
      gload16(Bg + (size_t)r0_ * 384 + (k0) + sw0_, Bs + (buf)*4096 + (w * 32) * 32);  \
      gload16(Bg + (size_t)r1_ * 384 + (k0) + sw1_, Bs + (buf)*4096 + (w * 32 + 16) * 32); \
    }                                                                                \
  }

#define QITER_QF(vmstr, gmod3, STG)                                                  \
  asm volatile("s_waitcnt vmcnt(" vmstr ")" ::: "memory");                           \
  __builtin_amdgcn_s_barrier();                                                      \
  STG;                                                                               \
  {                                                                                  \
    const float* Af_ = Asf + (gmod3) * 4096;                                         \
    const unsigned short* Bc_ = Bs + (gmod3) * 4096;                                 \
    bf16x8 a_[4], b_[4];                                                             \
    _Pragma("unroll") for (int mt = 0; mt < 4; ++mt) {                               \
      const int R = wm * 64 + mt * 16 + lq;                                          \
      float f_[8];                                                                   \
      *(float4*)&f_[0] = *(const float4*)&Af_[R * 32 + ((2 * lg) ^ (R & 7)) * 4];    \
      *(float4*)&f_[4] = *(const float4*)&Af_[R * 32 + ((2 * lg + 1) ^ (R & 7)) * 4]; \
      _Pragma("unroll") for (int e_ = 0; e_ < 8; ++e_)                               \
        a_[mt][e_] = (short)f2bf(f_[e_]);                                            \
    }                                                                                \
    _Pragma("unroll") for (int nt = 0; nt < 4; ++nt) {                               \
      const int R = wn * 64 + nt * 16 + lq;                                          \
      b_[nt] = *(const bf16x8*)&Bc_[R * 32 + 8 * (lg ^ ((R >> 1) & 3))];             \
    }                                                                                \
    _Pragma("unroll") for (int mt = 0; mt < 4; ++mt)                                 \
      _Pragma("unroll") for (int nt = 0; nt < 4; ++nt)                               \
        acc[mt][nt] = __builtin_amdgcn_mfma_f32_16x16x32_bf16(a_[mt], b_[nt], acc[mt][nt], 0, 0, 0); \
  }

// ---------------- Kernel 1: qkv = x(fp32) @ WqT^T + b_qkv -> packed bf16 [3][B][H][T][48]
__global__ __launch_bounds__(256) void k_qkv(const float* __restrict__ xg,
                                             const unsigned short* __restrict__ WqT,
                                             const float* __restrict__ bq,
                                             unsigned short* __restrict__ qkv) {
  __shared__ __align__(16) float Asf[3 * 4096];           // 48 KB fp32 A ring
  __shared__ __align__(16) unsigned short Bs[3 * 4096];   // 24 KB bf16 B ring
  const int t = threadIdx.x, lane = t & 63, w = t >> 6;
  const int wm = w >> 1, wn = w & 1;
  const int lq = lane & 15, lg = lane >> 4;
  const int swz = (blockIdx.x & 7) * 288 + (blockIdx.x >> 3);  // 2304 = 8*288
  const int m0 = (swz / 9) * 128, n0 = (swz % 9) * 128;
  const int comp = n0 / 384;
  const unsigned short* Bg = WqT + (size_t)n0 * 384;
  floatx4 acc[4][4] = {};

  STAGE_QF(0, 0);
  STAGE_QF(32, 1);
  QITER_QF("6", 0, STAGE_QF(64, 2));
  QITER_QF("6", 1, STAGE_QF(96, 0));
  QITER_QF("6", 2, STAGE_QF(128, 1));
  QITER_QF("6", 0, STAGE_QF(160, 2));
  QITER_QF("6", 1, STAGE_QF(192, 0));
  QITER_QF("6", 2, STAGE_QF(224, 1));
  QITER_QF("6", 0, STAGE_QF(256, 2));
  QITER_QF("6", 1, STAGE_QF(288, 0));
  QITER_QF("6", 2, STAGE_QF(320, 1));
  QITER_QF("6", 0, STAGE_QF(352, 2));
  QITER_QF("6", 1, {});
  QITER_QF("0", 2, {});

  // epilogue: transpose via dead Bs slices -> wide packed stores (r12-proven)
  __builtin_amdgcn_s_barrier();
  unsigned short* Ew = Bs + w * 2048;  // 4 waves x 2048 <= 12288
#pragma unroll
  for (int p = 0; p < 4; ++p) {
#pragma unroll
    for (int nt = 0; nt < 4; ++nt) {
      const float bias = bq[n0 + wn * 64 + nt * 16 + lq];
#pragma unroll
      for (int j = 0; j < 4; ++j)
        Ew[(lg * 4 + j) * 72 + nt * 16 + lq] = f2bf(acc[p][nt][j] + bias);
    }
    asm volatile("s_waitcnt lgkmcnt(0)" ::: "memory");
    __builtin_amdgcn_sched_barrier(0);
#pragma unroll
    for (int cc = 0; cc < 2; ++cc) {
      const int c = cc * 64 + lane;
      const int r16 = c >> 3, k8 = c & 7;
      bf16x8 v = *(const bf16x8*)&Ew[r16 * 72 + k8 * 8];
      const int lc = n0 - comp * 384 + wn * 64 + k8 * 8;
      const int hh = lc / 48, d0 = lc - hh * 48;
      const int R = m0 + wm * 64 + p * 16 + r16;
      *(bf16x8*)(qkv + (size_t)comp * CPLANE +
                 (((size_t)((R >> 8) * 8 + hh) * 256 + (R & 255)) * 48 + d0)) = v;
    }
    asm volatile("s_waitcnt lgkmcnt(0)" ::: "memory");
    __builtin_amdgcn_sched_barrier(0);
  }
}

// ====== r12 bf16 GEMM core (for k_proj) ======
#define STAGE_G(Ag, Bg, k0, buf)                                                     \
  {                                                                                  \
    const int r0_ = (lane >> 2), sw0_ = 8 * ((lane & 3) ^ ((r0_ >> 1) & 3));         \
    const int r1_ = r0_ + 16,    sw1_ = 8 * ((lane & 3) ^ ((r1_ >> 1) & 3));         \
    gload16((Ag) + (size_t)r0_ * 384 + (k0) + sw0_, As + (buf)*4096 + (w * 32) * 32);  \
    gload16((Ag) + (size_t)r1_ * 384 + (k0) + sw1_, As + (buf)*4096 + (w * 32 + 16) * 32); \
    gload16((Bg) + (size_t)r0_ * 384 + (k0) + sw0_, Bs + (buf)*4096 + (w * 32) * 32);  \
    gload16((Bg) + (size_t)r1_ * 384 + (k0) + sw1_, Bs + (buf)*4096 + (w * 32 + 16) * 32); \
  }

#define GEMM_PIPE(Ag, Bg)                                                            \
  STAGE_G(Ag, Bg, 0, 0);                                                             \
  STAGE_G(Ag, Bg, 32, 1);                                                            \
  _Pragma("unroll") for (int t_ = 0; t_ < 12; ++t_) {                                \
    if (t_ < 11) asm volatile("s_waitcnt vmcnt(4)" ::: "memory");                    \
    else         asm volatile("s_waitcnt vmcnt(0)" ::: "memory");                    \
    __builtin_amdgcn_s_barrier();                                                    \
    if (t_ < 10) STAGE_G(Ag, Bg, (t_ + 2) * 32, (t_ + 2) % 3);                       \
    const unsigned short* Ac_ = As + (t_ % 3) * 4096;                                \
    const unsigned short* Bc_ = Bs + (t_ % 3) * 4096;                                \
    bf16x8 a_[4], b_[4];                                                             \
    _Pragma("unroll") for (int mt = 0; mt < 4; ++mt) {                               \
      const int R = wm * 64 + mt * 16 + lq;                                          \
      a_[mt] = *(const bf16x8*)&Ac_[R * 32 + 8 * (lg ^ ((R >> 1) & 3))];             \
    }                                                                                \
    _Pragma("unroll") for (int nt = 0; nt < 4; ++nt) {                               \
      const int R = wn * 64 + nt * 16 + lq;                                          \
      b_[nt] = *(const bf16x8*)&Bc_[R * 32 + 8 * (lg ^ ((R >> 1) & 3))];             \
    }                                                                                \
    _Pragma("unroll") for (int mt = 0; mt < 4; ++mt)                                 \
      _Pragma("unroll") for (int nt = 0; nt < 4; ++nt)                               \
        acc[mt][nt] = __builtin_amdgcn_mfma_f32_16x16x32_bf16(a_[mt], b_[nt], acc[mt][nt], 0, 0, 0); \
  }

// ---------------- Kernel 3: out = attg @ WpT^T + b_proj (fp32 out; gate pre-folded)
__global__ __launch_bounds__(256) void k_proj(const unsigned short* __restrict__ A,
                                              const unsigned short* __restrict__ WpT,
                                              const float* __restrict__ bp,
                                              float* __restrict__ out) {
  __shared__ __align__(16) unsigned short As[3 * 4096];
  __shared__ __align__(16) unsigned short Bs[3 * 4096];
  const int t = threadIdx.x, lane = t & 63, w = t >> 6;
  const int wm = w >> 1, wn = w & 1;
  const int lq = lane & 15, lg = lane >> 4;
  const int swz = (blockIdx.x & 7) * 96 + (blockIdx.x >> 3);   // 768 = 8*96
  const int m0 = (swz / 3) * 128, n0 = (swz % 3) * 128;
  const unsigned short* Ag = A + (size_t)(m0 + w * 32) * 384;
  const unsigned short* Bg = WpT + (size_t)(n0 + w * 32) * 384;
  floatx4 acc[4][4] = {};

  GEMM_PIPE(Ag, Bg);

#pragma unroll
  for (int nt = 0; nt < 4; ++nt) {
    const int col = n0 + wn * 64 + nt * 16 + lq;
    const float bias = bp[col];
#pragma unroll
    for (int mt = 0; mt < 4; ++mt)
#pragma unroll
      for (int j = 0; j < 4; ++j) {
        const int row = m0 + wm * 64 + mt * 16 + lg * 4 + j;
        out[(size_t)row * 384 + col] = acc[mt][nt][j] + bias;
      }
  }
}

// ---------------- Kernel 2: windowed causal attention, one block per (b,h).
// (byte-identical to r12: K/V staged once, per-subtile hardening barrier)
__global__ __launch_bounds__(256) void k_attn(const unsigned short* __restrict__ qkv,
                                              unsigned short* __restrict__ attg) {
  __shared__ __align__(16) unsigned short Ks[256 * 72];      // [key][hd pad 64->72]
  __shared__ __align__(16) unsigned short Vt[48 * 280];      // [d][key pad 256->280]
  __shared__ __align__(16) unsigned short Ps[4 * 16 * 104];  // per-wave P [q][key pad]
  const int t = threadIdx.x;
  const int bh = blockIdx.x;
  const int b = bh >> 3, h = bh & 7;
  const size_t kvoff = (size_t)bh * NT * ND;
  const unsigned short* qptr = qkv + kvoff;
  const unsigned short* kptr = qkv + (size_t)CPLANE + kvoff;
  const unsigned short* vptr = qkv + (size_t)2 * CPLANE + kvoff;

  {  // stage K row t (all 256 keys), hd zero-padded 48..63
    const unsigned short* src = kptr + (size_t)t * ND;
    unsigned short* dst = &Ks[t * 72];
#pragma unroll
    for (int i = 0; i < 6; ++i) *(bf16x8*)(dst + i * 8) = *(const bf16x8*)(src + i * 8);
    bf16x8 z = {};
    *(bf16x8*)(dst + 48) = z;
    *(bf16x8*)(dst + 56) = z;
  }
  {  // stage V^T: thread t = key t, scatter 48 scalars
    const unsigned short* src = vptr + (size_t)t * ND;
    bf16x8 vv[6];
#pragma unroll
    for (int i = 0; i < 6; ++i) vv[i] = *(const bf16x8*)(src + i * 8);
#pragma unroll
    for (int i = 0; i < 6; ++i)
#pragma unroll
      for (int j = 0; j < 8; ++j)
        Vt[(i * 8 + j) * 280 + t] = (unsigned short)vv[i][j];
  }
  if (t < 144) {  // zero V pad cols 256..279
    bf16x8 z = {};
    *(bf16x8*)&Vt[(t / 3) * 280 + 256 + (t % 3) * 8] = z;
  }
  __syncthreads();

  const int lane = t & 63, w = t >> 6;
  const int lq = lane & 15, lg = lane >> 4;
  const float scale = 0.14433756729740643f;  // 1/sqrt(48)
  unsigned short* pw = &Ps[w * 16 * 104];

  for (int s = 0; s < 4; ++s) {
    const int qs = s * 64 + w * 16;
    const int kstart = (qs >= 64) ? (qs - 64) : 0;

    const unsigned short* qrow = qptr + (size_t)(qs + lq) * ND;
    bf16x8 aq0 = *(const bf16x8*)(qrow + lg * 8);
    bf16x8 aq1 = {};
    if (lg < 2) aq1 = *(const bf16x8*)(qrow + 32 + lg * 8);

    floatx4 sv4[5];
#pragma unroll
    for (int kt = 0; kt < 5; ++kt) {
      const unsigned short* kr = &Ks[(kstart + kt * 16 + lq) * 72];
      bf16x8 kb0 = *(const bf16x8*)(kr + lg * 8);
      bf16x8 kb1 = *(const bf16x8*)(kr + 32 + lg * 8);
      floatx4 z = {};
      z = __builtin_amdgcn_mfma_f32_16x16x32_bf16(aq0, kb0, z, 0, 0, 0);
      z = __builtin_amdgcn_mfma_f32_16x16x32_bf16(aq1, kb1, z, 0, 0, 0);
      sv4[kt] = z;
    }

    floatx4 pj[5];
#pragma unroll
    for (int j = 0; j < 4; ++j) {
      const int qa = qs + lg * 4 + j;
      float mx = -1e30f;
      float sv[5];
      bool ok[5];
#pragma unroll
      for (int kt = 0; kt < 5; ++kt) {
        const int ka = kstart + kt * 16 + lq;
        sv[kt] = sv4[kt][j] * scale;
        ok[kt] = (ka <= qa) && (qa - ka <= 64);
        if (ok[kt]) mx = fmaxf(mx, sv[kt]);
      }
#pragma unroll
      for (int dd = 1; dd < 16; dd <<= 1) mx = fmaxf(mx, __shfl_xor(mx, dd));
      float sum = 0.f;
#pragma unroll
      for (int kt = 0; kt < 5; ++kt) {
        float p = ok[kt] ? __expf(sv[kt] - mx) : 0.f;
        pj[kt][j] = p;
        sum += p;
      }
#pragma unroll
      for (int dd = 1; dd < 16; dd <<= 1) sum += __shfl_xor(sum, dd);
      const float inv = 1.f / sum;
#pragma unroll
      for (int kt = 0; kt < 5; ++kt) pj[kt][j] *= inv;
    }

#pragma unroll
    for (int kt = 0; kt < 5; ++kt)
#pragma unroll
      for (int j = 0; j < 4; ++j)
        pw[(lg * 4 + j) * 104 + kt * 16 + lq] = f2bf(pj[kt][j]);
#pragma unroll
    for (int j = 0; j < 4; ++j) pw[lq * 104 + 80 + lg * 4 + j] = 0;

    floatx4 o[3] = {};
#pragma unroll
    for (int c = 0; c < 3; ++c) {
      bf16x8 ap = *(const bf16x8*)&pw[lq * 104 + c * 32 + lg * 8];
#pragma unroll
      for (int nt = 0; nt < 3; ++nt) {
        bf16x8 av = *(const bf16x8*)&Vt[(nt * 16 + lq) * 280 + kstart + c * 32 + lg * 8];
        o[nt] = __builtin_amdgcn_mfma_f32_16x16x32_bf16(ap, av, o[nt], 0, 0, 0);
      }
    }
#pragma unroll
    for (int nt = 0; nt < 3; ++nt) {
      const int d = nt * 16 + lq;
      const int c = h * ND + d;
#pragma unroll
      for (int j = 0; j < 4; ++j) {
        const int tt = qs + lg * 4 + j;
        attg[((size_t)b * NT + tt) * NC + c] = f2bf(o[nt][j]);
      }
    }
    __syncthreads();  // hardening: no inter-wave overlap across subtile iterations
  }
}

extern "C" void kernel_launch(void* const* d_in, const int* in_sizes, int n_in,
                              void* d_out, int out_size, void* d_ws, size_t ws_size,
                              hipStream_t stream) {
  const float* x    = (const float*)d_in[0];
  const float* Wq   = (const float*)d_in[1];
  const float* bq   = (const float*)d_in[2];
  const float* Wp   = (const float*)d_in[3];
  const float* bp   = (const float*)d_in[4];
  const float* gate = (const float*)d_in[5];

  const size_t nx = (size_t)NB * NT * NC;                // 12,582,912
  unsigned short* attg = (unsigned short*)d_ws;
  unsigned short* qkvp = attg + nx;                      // packed [3][B][H][T][48]
  unsigned short* WqT  = qkvp + (size_t)3 * CPLANE;
  unsigned short* WpT  = WqT + (size_t)384 * 1152;
  float* out = (float*)d_out;

  k_prep<<<dim3(144), 256, 0, stream>>>(Wq, Wp, gate, WqT, WpT);
  k_qkv<<<dim3(2304), 256, 0, stream>>>(x, WqT, bq, qkvp);
  k_attn<<<dim3(1024), 256, 0, stream>>>(qkvp, attg);
  k_proj<<<dim3(768), 256, 0, stream>>>(attg, WpT, bp, out);
}

// Round 15
// 110.903 us; speedup vs baseline: 1.0386x; 1.0386x over previous
//
#include <hip/hip_runtime.h>
#include <hip/hip_bf16.h>

typedef __attribute__((ext_vector_type(8))) short bf16x8;
typedef __attribute__((ext_vector_type(4))) float floatx4;

#define NB 128
#define NT 256
#define NC 384
#define NH 8
#define ND 48
#define CPLANE (128 * 8 * 256 * 48)  // elems per qkv component plane

static __device__ __forceinline__ unsigned short f2bf(float f) {
  __hip_bfloat16 h = __float2bfloat16(f);
  return __builtin_bit_cast(unsigned short, h);
}

static __device__ __forceinline__ void gload16(const unsigned short* g, unsigned short* l) {
  __builtin_amdgcn_global_load_lds(
      (const __attribute__((address_space(1))) void*)g,
      (__attribute__((address_space(3))) void*)l, 16, 0, 0);
}

// ---------------- Prep: W_qkv^T -> [1152][384] bf16, W_proj^T (gate folded) -> [384][384],
//                  x fp32 -> bf16.  (byte-identical to r12)
__global__ __launch_bounds__(256) void k_prep(const float* __restrict__ x,
                                              const float* __restrict__ Wq,
                                              const float* __restrict__ Wp,
                                              const float* __restrict__ gate,
                                              unsigned short* __restrict__ xbf,
                                              unsigned short* __restrict__ WqT,
                                              unsigned short* __restrict__ WpT) {
  const int blk = blockIdx.x;
  const int t = threadIdx.x;
  if (blk < 144) {
    __shared__ float T[64][65];
    const float* src;
    unsigned short* dst;
    int N, kt, nt;
    const bool isWp = (blk >= 108);
    if (!isWp) { src = Wq; dst = WqT; N = 1152; kt = blk / 18; nt = blk % 18; }
    else { int b2 = blk - 108; src = Wp; dst = WpT; N = 384; kt = b2 / 6; nt = b2 % 6; }
    const int k0 = kt * 64, n0 = nt * 64;
    const int r = t >> 2, c = (t & 3) * 16;
    const float* s = src + (size_t)(k0 + r) * N + n0 + c;
#pragma unroll
    for (int i = 0; i < 4; ++i) *(float4*)&T[r][c + i * 4] = ((const float4*)s)[i];
    __syncthreads();
    float gv[16];
    if (isWp) {
#pragma unroll
      for (int i = 0; i < 4; ++i) *(float4*)&gv[i * 4] = ((const float4*)(gate + k0 + c))[i];
    } else {
#pragma unroll
      for (int i = 0; i < 16; ++i) gv[i] = 1.f;
    }
    unsigned short o[16];
#pragma unroll
    for (int i = 0; i < 16; ++i) o[i] = f2bf(T[c + i][r] * gv[i]);
    unsigned short* dp = dst + (size_t)(n0 + r) * 384 + k0 + c;
    *(bf16x8*)dp = *(bf16x8*)&o[0];
    *(bf16x8*)(dp + 8) = *(bf16x8*)&o[8];
  } else {
    const int n8 = (NB * NT * NC) / 8;
    int idx = (blk - 144) * 256 + t;
    const int stride = (gridDim.x - 144) * 256;
    for (; idx < n8; idx += stride) {
      const float* s = x + (size_t)idx * 8;
      float v[8];
      *(float4*)&v[0] = ((const float4*)s)[0];
      *(float4*)&v[4] = ((const float4*)s)[1];
      bf16x8 p;
#pragma unroll
      for (int i = 0; i < 8; ++i) p[i] = f2bf(v[i]);
      *(bf16x8*)(xbf + (size_t)idx * 8) = p;
    }
  }
}

// ====== r7/r12-proven staging: 128x32 tile, source XOR-swizzle, linear LDS dest ======
#define STAGE_G(Ag, Bg, k0, buf)                                                     \
  {                                                                                  \
    const int r0_ = (lane >> 2), sw0_ = 8 * ((lane & 3) ^ ((r0_ >> 1) & 3));         \
    const int r1_ = r0_ + 16,    sw1_ = 8 * ((lane & 3) ^ ((r1_ >> 1) & 3));         \
    gload16((Ag) + (size_t)r0_ * 384 + (k0) + sw0_, As + (buf)*4096 + (w * 32) * 32);  \
    gload16((Ag) + (size_t)r1_ * 384 + (k0) + sw1_, As + (buf)*4096 + (w * 32 + 16) * 32); \
    gload16((Bg) + (size_t)r0_ * 384 + (k0) + sw0_, Bs + (buf)*4096 + (w * 32) * 32);  \
    gload16((Bg) + (size_t)r1_ * 384 + (k0) + sw1_, Bs + (buf)*4096 + (w * 32 + 16) * 32); \
  }

// r12-proven K-loop: 12 iters, 3 buffers, counted vmcnt(4), 1 barrier per iter
#define GEMM_PIPE(Ag, Bg)                                                            \
  STAGE_G(Ag, Bg, 0, 0);                                                             \
  STAGE_G(Ag, Bg, 32, 1);                                                            \
  _Pragma("unroll") for (int t_ = 0; t_ < 12; ++t_) {                                \
    if (t_ < 11) asm volatile("s_waitcnt vmcnt(4)" ::: "memory");                    \
    else         asm volatile("s_waitcnt vmcnt(0)" ::: "memory");                    \
    __builtin_amdgcn_s_barrier();                                                    \
    if (t_ < 10) STAGE_G(Ag, Bg, (t_ + 2) * 32, (t_ + 2) % 3);                       \
    const unsigned short* Ac_ = As + (t_ % 3) * 4096;                                \
    const unsigned short* Bc_ = Bs + (t_ % 3) * 4096;                                \
    bf16x8 a_[4], b_[4];                                                             \
    _Pragma("unroll") for (int mt = 0; mt < 4; ++mt) {                               \
      const int R = wm * 64 + mt * 16 + lq;                                          \
      a_[mt] = *(const bf16x8*)&Ac_[R * 32 + 8 * (lg ^ ((R >> 1) & 3))];             \
    }                                                                                \
    _Pragma("unroll") for (int nt = 0; nt < 4; ++nt) {                               \
      const int R = wn * 64 + nt * 16 + lq;                                          \
      b_[nt] = *(const bf16x8*)&Bc_[R * 32 + 8 * (lg ^ ((R >> 1) & 3))];             \
    }                                                                                \
    _Pragma("unroll") for (int mt = 0; mt < 4; ++mt)                                 \
      _Pragma("unroll") for (int nt = 0; nt < 4; ++nt)                               \
        acc[mt][nt] = __builtin_amdgcn_mfma_f32_16x16x32_bf16(a_[mt], b_[nt], acc[mt][nt], 0, 0, 0); \
  }

// ---------------- Kernel 1: qkv = xb @ WqT^T + b_qkv -> packed bf16 [3][B][H][T][48]
// (byte-identical to r12)
__global__ __launch_bounds__(256) void k_qkv(const unsigned short* __restrict__ xb,
                                             const unsigned short* __restrict__ WqT,
                                             const float* __restrict__ bq,
                                             unsigned short* __restrict__ qkv) {
  __shared__ __align__(16) unsigned short As[3 * 4096];
  __shared__ __align__(16) unsigned short Bs[3 * 4096];
  const int t = threadIdx.x, lane = t & 63, w = t >> 6;
  const int wm = w >> 1, wn = w & 1;
  const int lq = lane & 15, lg = lane >> 4;
  const int swz = (blockIdx.x & 7) * 288 + (blockIdx.x >> 3);  // 2304 = 8*288
  const int m0 = (swz / 9) * 128, n0 = (swz % 9) * 128;
  const int comp = n0 / 384;
  const unsigned short* Ag = xb + (size_t)(m0 + w * 32) * 384;
  const unsigned short* Bg = WqT + (size_t)(n0 + w * 32) * 384;
  floatx4 acc[4][4] = {};

  GEMM_PIPE(Ag, Bg);

  // epilogue: all reads of buf2 done (last QITER) -> barrier -> reuse buf2 slices
  __builtin_amdgcn_s_barrier();
  unsigned short* Ew = ((w < 2) ? As : Bs) + 2 * 4096 + (w & 1) * 2048;  // 2048 elems
#pragma unroll
  for (int p = 0; p < 4; ++p) {  // 16-row strip: transpose + bias, then 2 wide stores
#pragma unroll
    for (int nt = 0; nt < 4; ++nt) {
      const float bias = bq[n0 + wn * 64 + nt * 16 + lq];
#pragma unroll
      for (int j = 0; j < 4; ++j)
        Ew[(lg * 4 + j) * 72 + nt * 16 + lq] = f2bf(acc[p][nt][j] + bias);
    }
    asm volatile("s_waitcnt lgkmcnt(0)" ::: "memory");
    __builtin_amdgcn_sched_barrier(0);
#pragma unroll
    for (int cc = 0; cc < 2; ++cc) {
      const int c = cc * 64 + lane;
      const int r16 = c >> 3, k8 = c & 7;
      bf16x8 v = *(const bf16x8*)&Ew[r16 * 72 + k8 * 8];
      const int lc = n0 - comp * 384 + wn * 64 + k8 * 8;  // local col in comp
      const int hh = lc / 48, d0 = lc - hh * 48;          // 8-chunks never cross heads
      const int R = m0 + wm * 64 + p * 16 + r16;
      *(bf16x8*)(qkv + (size_t)comp * CPLANE +
                 (((size_t)((R >> 8) * 8 + hh) * 256 + (R & 255)) * 48 + d0)) = v;
    }
    asm volatile("s_waitcnt lgkmcnt(0)" ::: "memory");
    __builtin_amdgcn_sched_barrier(0);
  }
}

// ---------------- Kernel 3: out = attg @ WpT^T + b_proj (fp32 out; gate pre-folded)
// (byte-identical to r12)
__global__ __launch_bounds__(256) void k_proj(const unsigned short* __restrict__ A,
                                              const unsigned short* __restrict__ WpT,
                                              const float* __restrict__ bp,
                                              float* __restrict__ out) {
  __shared__ __align__(16) unsigned short As[3 * 4096];
  __shared__ __align__(16) unsigned short Bs[3 * 4096];
  const int t = threadIdx.x, lane = t & 63, w = t >> 6;
  const int wm = w >> 1, wn = w & 1;
  const int lq = lane & 15, lg = lane >> 4;
  const int swz = (blockIdx.x & 7) * 96 + (blockIdx.x >> 3);   // 768 = 8*96
  const int m0 = (swz / 3) * 128, n0 = (swz % 3) * 128;
  const unsigned short* Ag = A + (size_t)(m0 + w * 32) * 384;
  const unsigned short* Bg = WpT + (size_t)(n0 + w * 32) * 384;
  floatx4 acc[4][4] = {};

  GEMM_PIPE(Ag, Bg);

#pragma unroll
  for (int nt = 0; nt < 4; ++nt) {
    const int col = n0 + wn * 64 + nt * 16 + lq;
    const float bias = bp[col];
#pragma unroll
    for (int mt = 0; mt < 4; ++mt)
#pragma unroll
      for (int j = 0; j < 4; ++j) {
        const int row = m0 + wm * 64 + mt * 16 + lg * 4 + j;
        out[(size_t)row * 384 + col] = acc[mt][nt][j] + bias;
      }
  }
}

// ---------------- Kernel 2: windowed causal attention, one block per (b,h).
// r12 structure + T5 setprio around MFMA clusters (2 independent blocks/CU ->
// waves at different phases; m191 regime).
__global__ __launch_bounds__(256) void k_attn(const unsigned short* __restrict__ qkv,
                                              unsigned short* __restrict__ attg) {
  __shared__ __align__(16) unsigned short Ks[256 * 72];      // [key][hd pad 64->72]
  __shared__ __align__(16) unsigned short Vt[48 * 280];      // [d][key pad 256->280]
  __shared__ __align__(16) unsigned short Ps[4 * 16 * 104];  // per-wave P [q][key pad]
  const int t = threadIdx.x;
  const int bh = blockIdx.x;
  const int b = bh >> 3, h = bh & 7;
  const size_t kvoff = (size_t)bh * NT * ND;
  const unsigned short* qptr = qkv + kvoff;
  const unsigned short* kptr = qkv + (size_t)CPLANE + kvoff;
  const unsigned short* vptr = qkv + (size_t)2 * CPLANE + kvoff;

  {  // stage K row t (all 256 keys), hd zero-padded 48..63
    const unsigned short* src = kptr + (size_t)t * ND;
    unsigned short* dst = &Ks[t * 72];
#pragma unroll
    for (int i = 0; i < 6; ++i) *(bf16x8*)(dst + i * 8) = *(const bf16x8*)(src + i * 8);
    bf16x8 z = {};
    *(bf16x8*)(dst + 48) = z;
    *(bf16x8*)(dst + 56) = z;
  }
  {  // stage V^T: thread t = key t, scatter 48 scalars
    const unsigned short* src = vptr + (size_t)t * ND;
    bf16x8 vv[6];
#pragma unroll
    for (int i = 0; i < 6; ++i) vv[i] = *(const bf16x8*)(src + i * 8);
#pragma unroll
    for (int i = 0; i < 6; ++i)
#pragma unroll
      for (int j = 0; j < 8; ++j)
        Vt[(i * 8 + j) * 280 + t] = (unsigned short)vv[i][j];
  }
  if (t < 144) {  // zero V pad cols 256..279
    bf16x8 z = {};
    *(bf16x8*)&Vt[(t / 3) * 280 + 256 + (t % 3) * 8] = z;
  }
  __syncthreads();

  const int lane = t & 63, w = t >> 6;
  const int lq = lane & 15, lg = lane >> 4;
  const float scale = 0.14433756729740643f;  // 1/sqrt(48)
  unsigned short* pw = &Ps[w * 16 * 104];

  for (int s = 0; s < 4; ++s) {
    const int qs = s * 64 + w * 16;
    const int kstart = (qs >= 64) ? (qs - 64) : 0;

    const unsigned short* qrow = qptr + (size_t)(qs + lq) * ND;
    bf16x8 aq0 = *(const bf16x8*)(qrow + lg * 8);
    bf16x8 aq1 = {};
    if (lg < 2) aq1 = *(const bf16x8*)(qrow + 32 + lg * 8);

    floatx4 sv4[5];
    __builtin_amdgcn_s_setprio(1);
#pragma unroll
    for (int kt = 0; kt < 5; ++kt) {
      const unsigned short* kr = &Ks[(kstart + kt * 16 + lq) * 72];
      bf16x8 kb0 = *(const bf16x8*)(kr + lg * 8);
      bf16x8 kb1 = *(const bf16x8*)(kr + 32 + lg * 8);
      floatx4 z = {};
      z = __builtin_amdgcn_mfma_f32_16x16x32_bf16(aq0, kb0, z, 0, 0, 0);
      z = __builtin_amdgcn_mfma_f32_16x16x32_bf16(aq1, kb1, z, 0, 0, 0);
      sv4[kt] = z;
    }
    __builtin_amdgcn_s_setprio(0);

    floatx4 pj[5];
#pragma unroll
    for (int j = 0; j < 4; ++j) {
      const int qa = qs + lg * 4 + j;
      float mx = -1e30f;
      float sv[5];
      bool ok[5];
#pragma unroll
      for (int kt = 0; kt < 5; ++kt) {
        const int ka = kstart + kt * 16 + lq;
        sv[kt] = sv4[kt][j] * scale;
        ok[kt] = (ka <= qa) && (qa - ka <= 64);
        if (ok[kt]) mx = fmaxf(mx, sv[kt]);
      }
#pragma unroll
      for (int dd = 1; dd < 16; dd <<= 1) mx = fmaxf(mx, __shfl_xor(mx, dd));
      float sum = 0.f;
#pragma unroll
      for (int kt = 0; kt < 5; ++kt) {
        float p = ok[kt] ? __expf(sv[kt] - mx) : 0.f;
        pj[kt][j] = p;
        sum += p;
      }
#pragma unroll
      for (int dd = 1; dd < 16; dd <<= 1) sum += __shfl_xor(sum, dd);
      const float inv = 1.f / sum;
#pragma unroll
      for (int kt = 0; kt < 5; ++kt) pj[kt][j] *= inv;
    }

#pragma unroll
    for (int kt = 0; kt < 5; ++kt)
#pragma unroll
      for (int j = 0; j < 4; ++j)
        pw[(lg * 4 + j) * 104 + kt * 16 + lq] = f2bf(pj[kt][j]);
#pragma unroll
    for (int j = 0; j < 4; ++j) pw[lq * 104 + 80 + lg * 4 + j] = 0;

    floatx4 o[3] = {};
    __builtin_amdgcn_s_setprio(1);
#pragma unroll
    for (int c = 0; c < 3; ++c) {
      bf16x8 ap = *(const bf16x8*)&pw[lq * 104 + c * 32 + lg * 8];
#pragma unroll
      for (int nt = 0; nt < 3; ++nt) {
        bf16x8 av = *(const bf16x8*)&Vt[(nt * 16 + lq) * 280 + kstart + c * 32 + lg * 8];
        o[nt] = __builtin_amdgcn_mfma_f32_16x16x32_bf16(ap, av, o[nt], 0, 0, 0);
      }
    }
    __builtin_amdgcn_s_setprio(0);
#pragma unroll
    for (int nt = 0; nt < 3; ++nt) {
      const int d = nt * 16 + lq;
      const int c = h * ND + d;
#pragma unroll
      for (int j = 0; j < 4; ++j) {
        const int tt = qs + lg * 4 + j;
        attg[((size_t)b * NT + tt) * NC + c] = f2bf(o[nt][j]);
      }
    }
    __syncthreads();  // hardening: no inter-wave overlap across subtile iterations
  }
}

extern "C" void kernel_launch(void* const* d_in, const int* in_sizes, int n_in,
                              void* d_out, int out_size, void* d_ws, size_t ws_size,
                              hipStream_t stream) {
  const float* x    = (const float*)d_in[0];
  const float* Wq   = (const float*)d_in[1];
  const float* bq   = (const float*)d_in[2];
  const float* Wp   = (const float*)d_in[3];
  const float* bp   = (const float*)d_in[4];
  const float* gate = (const float*)d_in[5];

  const size_t nx = (size_t)NB * NT * NC;                // 12,582,912
  unsigned short* attg = (unsigned short*)d_ws;
  unsigned short* xbf  = attg + nx;
  unsigned short* qkvp = xbf + nx;                       // packed [3][B][H][T][48]
  unsigned short* WqT  = qkvp + (size_t)3 * CPLANE;
  unsigned short* WpT  = WqT + (size_t)384 * 1152;
  float* out = (float*)d_out;

  k_prep<<<dim3(1680), 256, 0, stream>>>(x, Wq, Wp, gate, xbf, WqT, WpT);
  k_qkv<<<dim3(2304), 256, 0, stream>>>(xbf, WqT, bq, qkvp);
  k_attn<<<dim3(1024), 256, 0, stream>>>(qkvp, attg);
  k_proj<<<dim3(768), 256, 0, stream>>>(attg, WpT, bp, out);
}